// Round 6
// baseline (439.318 us; speedup 1.0000x reference)
//
#include <hip/hip_runtime.h>

typedef unsigned short u16;
typedef unsigned int   u32;
typedef _Float16       f16;
typedef _Float16 f16x8 __attribute__((ext_vector_type(8)));
typedef float    f32x4 __attribute__((ext_vector_type(4)));

#define B_  64
#define T_  300
#define V_  25
#define C_  64
#define ROWS (B_*T_)          // 19200
#define ROWE (V_*C_)          // 1600
#define NSTAT 480000.0f       // B*T*V
#define EPS_ 1e-5f
#define TTILE 30              // temporal tile (10 tiles of 30)
#define K2BLK 4800            // k2 blocks (4 rows each)
#define XFS 74                // xf row stride (halfs) — <=2-way banks
#define XWS 42                // xw row stride (halfs) — <=2-way banks

__device__ __forceinline__ float b2f(u16 u) {
    union { u32 i; float f; } v; v.i = ((u32)u) << 16; return v.f;
}
__device__ __forceinline__ u16 f2b(float f) {  // round-to-nearest-even
    union { float f; u32 i; } v; v.f = f;
    u32 x = v.i;
    u32 r = x + 0x7fffu + ((x >> 16) & 1u);
    return (u16)(r >> 16);
}
__device__ __forceinline__ u32 pk2h(float a, float b) {   // pack 2 f32 -> 2 f16
    union { f16 h[2]; u32 u; } p;
    p.h[0] = (f16)a; p.h[1] = (f16)b;
    return p.u;
}
__device__ __forceinline__ u16 h2u(float v) {             // f32 -> f16 bits
    union { f16 h; u16 u; } p; p.h = (f16)v; return p.u;
}
__device__ __forceinline__ float u2h(u16 u) {             // f16 bits -> f32
    union { u16 u; f16 h; } p; p.u = u; return (float)p.h;
}

template<bool F32>
__device__ __forceinline__ float ldv(const void* p, size_t i) {
    if (F32) return ((const float*)p)[i];
    return b2f(((const u16*)p)[i]);
}

// staging row stride in u16 units (fp32 mode: staging row r sits in the
// low half of fp32 output row r's byte range -> in-place overwrite is safe).
template<bool F32> struct Geo { static const int STR = F32 ? 3200 : 1600; };

// ---------------------------------------------------------------------------
// K0: dtype detection (device-side ground truth; host fast-path uses in_sizes)
// ---------------------------------------------------------------------------
__global__ void k0_detect(const void* W1raw, int* flag)
{
    __shared__ float red[256];
    const u16* p = (const u16*)W1raw;
    float mx = 0.0f;
    for (int i = threadIdx.x; i < 4096; i += 256) {
        float v = fabsf(b2f(p[i]));
        if (v == v) mx = fmaxf(mx, v);
    }
    red[threadIdx.x] = mx;
    __syncthreads();
    for (int s = 128; s > 0; s >>= 1) {
        if (threadIdx.x < s) red[threadIdx.x] = fmaxf(red[threadIdx.x], red[threadIdx.x + s]);
        __syncthreads();
    }
    if (threadIdx.x == 0) flag[0] = (red[0] > 1e10f) ? 1 : 0;
}

// ---------------------------------------------------------------------------
// K1: prep tables.
//   anf  : An^T fragments per branch (k2 phase-2 B-operand), [i3][nt2][64][8]:
//          value = An_i[v][u], v=nt*16+(lane&15), u=(lane>>4)*8+j (K=32,
//          zero for v>=25 or u>=25).                        (3072 f16)
//   wcatT: wcatT[i][c][k(pad 72)] = W_i[k][c], 13824 f16 (k2 phase-1 B).
//   wtT  : wtT[c][k(pad 72)] = Wt[k][c], 4608 f16 (k3 B-operand).
//   bsum : b1+b2+b3 (folded into BN1 mean, NOT added in k2).
// ---------------------------------------------------------------------------
template<bool F32>
__global__ void k1_prep(const int* __restrict__ flag,
                        const void* A, const void* E,
                        const void* W1, const void* W2, const void* W3,
                        const void* Wt,
                        const void* b1, const void* b2, const void* b3,
                        u16* __restrict__ anf, u16* __restrict__ wcatT,
                        u16* __restrict__ wtT, float* __restrict__ bsum)
{
    if (flag[0] != (F32 ? 1 : 0)) return;
    __shared__ float dinvL[75];
    const int tid = threadIdx.x;
    if (tid < 75) {
        int i = tid / 25, v = tid % 25;
        float d = 1.0f;                       // diagonal forced to 1
        for (int u = 0; u < 25; ++u)
            if (u != v) d += ldv<F32>(A, (i*25+v)*25+u) * ldv<F32>(E, (i*25+v)*25+u);
        dinvL[tid] = (d > 0.0f) ? rsqrtf(d) : 0.0f;
    }
    __syncthreads();
    // per-branch An^T fragments (K=32)
    for (int idx = tid; idx < 3072; idx += 256) {
        int fr = idx >> 9, lane = (idx >> 3) & 63, j = idx & 7;
        int i = fr >> 1, nt = fr & 1;
        int v = nt*16 + (lane & 15);
        int u = ((lane >> 4) << 3) + j;
        float val = 0.0f;
        if (v < 25 && u < 25) {
            float ad = (u == v) ? 1.0f
                     : ldv<F32>(A, (i*25+v)*25+u) * ldv<F32>(E, (i*25+v)*25+u);
            val = dinvL[i*25+v] * ad * dinvL[i*25+u];
        }
        anf[idx] = h2u(val);
    }
    // WcatT[i][c][k] = W_i[k][c], rows padded to 72 halfs
    for (int idx = tid; idx < 13824; idx += 256) {
        int i = idx / 4608;
        int rem = idx - i*4608;
        int c = rem / 72, k = rem - (rem/72)*72;
        float val = 0.0f;
        if (k < 64) {
            const void* W = (i == 0) ? W1 : ((i == 1) ? W2 : W3);
            val = ldv<F32>(W, k*64 + c);
        }
        wcatT[idx] = h2u(val);
    }
    // WtT[c][k] = Wt[k][c], rows padded to 72 halfs
    for (int idx = tid; idx < 4608; idx += 256) {
        int c = idx / 72, k = idx - (idx/72)*72;
        float val = (k < 64) ? ldv<F32>(Wt, k*64 + c) : 0.0f;
        wtT[idx] = h2u(val);
    }
    if (tid < 64) bsum[tid] = ldv<F32>(b1, tid) + ldv<F32>(b2, tid) + ldv<F32>(b3, tid);
}

// ---------------------------------------------------------------------------
// K2 (MFMA): R2-proven structure. 4 rows per block, grid 4800.
//   stage x (4 rows) -> xf LDS [m=r*28+u][XFS=74]
//   per branch i: phase1 xw[(r,c)][u] = x@W_i (7 mt strided over waves),
//                 sync, phase2 acc += xw@An_i^T, sync.
//   epilogue: out1 (no bias; BN absorbs), halo rows, BN1 partials -> p1[blk].
// ---------------------------------------------------------------------------
template<bool F32>
__global__ __launch_bounds__(256, 4) void k2_mfma(
    const int* __restrict__ flag, const void* x,
    const u16* __restrict__ wcatT, const u16* __restrict__ anf,
    u16* __restrict__ out1, u16* __restrict__ halo, float* __restrict__ p1)
{
    if (flag[0] != (F32 ? 1 : 0)) return;
    const int STR = Geo<F32>::STR;

    __shared__ f16 xf[112*XFS];    // 16.6 KB
    __shared__ u16 xw[256*XWS];    // 21.5 KB

    const int tid  = threadIdx.x;
    const int lane = tid & 63, w = tid >> 6;
    const int lo = lane & 15, hi = lane >> 4;
    const int r0   = blockIdx.x * 4;

    // ---- stage x (4 rows) as f16 into xf ----
    for (int q4 = tid; q4 < 1600; q4 += 256) {
        int r = (q4 * 10486) >> 22;          // q4/400
        int rem = q4 - 400*r;
        float v0, v1, v2, v3;
        if (F32) {
            float4 t4 = ((const float4*)x)[(size_t)(r0+r)*400 + rem];
            v0 = t4.x; v1 = t4.y; v2 = t4.z; v3 = t4.w;
        } else {
            ushort4 t4 = ((const ushort4*)x)[(size_t)(r0+r)*400 + rem];
            v0 = b2f(t4.x); v1 = b2f(t4.y); v2 = b2f(t4.z); v3 = b2f(t4.w);
        }
        int u = rem >> 4, k0 = (rem & 15) << 2;
        int m = r*28 + u;
        *(uint2*)&xf[m*XFS + k0] = make_uint2(pk2h(v0, v1), pk2h(v2, v3));
    }
    // zero x pad rows u=25..27 (12 rows x 74 halfs = 444 u32)
    for (int idx = tid; idx < 444; idx += 256) {
        int j   = idx / 37;                  // pad-row ordinal 0..11
        int off = idx - 37*j;
        int rr = j / 3, p = j - 3*rr;
        ((u32*)xf)[(rr*28 + 25 + p)*(XFS/2) + off] = 0u;
    }
    // zero xw u-pad [28,32)
    *(uint2*)&xw[tid*XWS + 28] = make_uint2(0u, 0u);

    // ---- preload An^T fragments ----
    f16x8 anfr[3][2];
    #pragma unroll
    for (int i = 0; i < 3; ++i)
        #pragma unroll
        for (int nt = 0; nt < 2; ++nt)
            anfr[i][nt] = *(const f16x8*)&anf[((i*2 + nt)*64 + lane)*8];

    const int c0 = w*16 + (hi << 2);        // this thread's 4 channels

    f32x4 acc[4][2];
    #pragma unroll
    for (int j = 0; j < 4; ++j) {
        acc[j][0] = f32x4{0.f, 0.f, 0.f, 0.f};
        acc[j][1] = f32x4{0.f, 0.f, 0.f, 0.f};
    }

    __syncthreads();

    #pragma unroll
    for (int i = 0; i < 3; ++i) {
        f16x8 wfr[4][2];
        #pragma unroll
        for (int nt = 0; nt < 4; ++nt)
            #pragma unroll
            for (int ks = 0; ks < 2; ++ks)
                wfr[nt][ks] = *(const f16x8*)&wcatT[
                    (size_t)(i*64 + nt*16 + lo)*72 + ks*32 + (hi << 3)];

        // ---- phase 1: xw = x @ W_i ----
        for (int mt = w; mt < 7; mt += 4) {
            const int arow = (mt*16 + lo)*XFS + (hi << 3);
            f16x8 a0 = *(const f16x8*)&xf[arow];
            f16x8 a1 = *(const f16x8*)&xf[arow + 32];
            const int m0 = mt*16 + (hi << 2);
            const int r  = (m0 * 293) >> 13;        // m0/28
            const int u0 = m0 - 28*r;
            #pragma unroll
            for (int nt = 0; nt < 4; ++nt) {
                f32x4 d = f32x4{0.f, 0.f, 0.f, 0.f};
                d = __builtin_amdgcn_mfma_f32_16x16x32_f16(a0, wfr[nt][0], d, 0, 0, 0);
                d = __builtin_amdgcn_mfma_f32_16x16x32_f16(a1, wfr[nt][1], d, 0, 0, 0);
                const int cc = nt*16 + lo;
                *(uint2*)&xw[(r*64 + cc)*XWS + u0] =
                    make_uint2(pk2h(d[0], d[1]), pk2h(d[2], d[3]));
            }
        }
        __syncthreads();

        // ---- phase 2: acc += xw @ An_i^T ----
        #pragma unroll
        for (int j = 0; j < 4; ++j) {
            const int mt2 = w + 4*j;
            f16x8 a = *(const f16x8*)&xw[(mt2*16 + lo)*XWS + (hi << 3)];
            acc[j][0] = __builtin_amdgcn_mfma_f32_16x16x32_f16(a, anfr[i][0], acc[j][0], 0, 0, 0);
            acc[j][1] = __builtin_amdgcn_mfma_f32_16x16x32_f16(a, anfr[i][1], acc[j][1], 0, 0, 0);
        }
        __syncthreads();
    }

    // ---- epilogue: out1 (+halo), BN1 partials, per-block p1 ----
    float ssum[4] = {0.f, 0.f, 0.f, 0.f}, ssq[4] = {0.f, 0.f, 0.f, 0.f};
    #pragma unroll
    for (int j = 0; j < 4; ++j) {          // row r0+j
        const int row = r0 + j;
        const int b = row / T_;
        const int t = row - b*T_;
        const int tm = t % TTILE;
        const bool hbd = (tm < 4) || (tm >= TTILE - 4);
        u16* hrow = nullptr;
        if (hbd) {
            const int slot = tm < 4 ? tm : tm - 22;
            hrow = halo + (((size_t)b*10 + t/TTILE)*8 + slot)*ROWE;
        }
        u16* orow = out1 + (size_t)row*STR;
        #pragma unroll
        for (int nt = 0; nt < 2; ++nt) {
            const int v = nt*16 + lo;
            if (v < 25) {
                float o0 = acc[j][nt][0];
                float o1 = acc[j][nt][1];
                float o2 = acc[j][nt][2];
                float o3 = acc[j][nt][3];
                ssum[0] += o0; ssq[0] += o0*o0;
                ssum[1] += o1; ssq[1] += o1*o1;
                ssum[2] += o2; ssq[2] += o2*o2;
                ssum[3] += o3; ssq[3] += o3*o3;
                ushort4 pk;
                pk.x = f2b(o0); pk.y = f2b(o1); pk.z = f2b(o2); pk.w = f2b(o3);
                *(ushort4*)&orow[v*64 + c0] = pk;
                if (hbd) *(ushort4*)&hrow[v*64 + c0] = pk;
            }
        }
    }
    #pragma unroll
    for (int t = 0; t < 4; ++t) {
        #pragma unroll
        for (int off = 1; off < 16; off <<= 1) {
            ssum[t] += __shfl_xor(ssum[t], off);
            ssq[t]  += __shfl_xor(ssq[t],  off);
        }
    }
    if (lo == 0) {
        #pragma unroll
        for (int t = 0; t < 4; ++t) {
            p1[(size_t)blockIdx.x*128 + c0 + t]      = ssum[t];
            p1[(size_t)blockIdx.x*128 + 64 + c0 + t] = ssq[t];
        }
    }
}

// ---------------------------------------------------------------------------
// K_reduce: parallel partial-sum reduce part[n][128] -> q[64][128]. dtype-free.
// ---------------------------------------------------------------------------
__global__ __launch_bounds__(128) void k_reduce(const float* __restrict__ in,
                                                int n, float* __restrict__ outq)
{
    const int t = threadIdx.x;
    float s = 0.0f;
    for (int r = blockIdx.x; r < n; r += 64) s += in[(size_t)r*128 + t];
    outq[(size_t)blockIdx.x*128 + t] = s;
}

// ---------------------------------------------------------------------------
// K_bnstats: finalize from q[64][128]. useb: add mb[c] to the mean (bias fold).
// ---------------------------------------------------------------------------
template<bool F32>
__global__ void k_bnstats(const int* __restrict__ flag,
                          const float* __restrict__ q,
                          const void* gamma, const void* beta,
                          const float* __restrict__ mb, int useb,
                          float* __restrict__ scale, float* __restrict__ shift)
{
    if (flag[0] != (F32 ? 1 : 0)) return;
    __shared__ float redL[512];
    const int tid = threadIdx.x, c = tid & 63, g = tid >> 6;   // g < 4
    float s = 0.0f, ssq = 0.0f;
    for (int r = g; r < 64; r += 4) { s += q[r*128 + c]; ssq += q[r*128 + 64 + c]; }
    redL[g*64 + c] = s; redL[256 + g*64 + c] = ssq;
    __syncthreads();
    if (tid < 64) {
        const float S  = redL[tid] + redL[64+tid] + redL[128+tid] + redL[192+tid];
        const float SS = redL[256+tid] + redL[320+tid] + redL[384+tid] + redL[448+tid];
        const float my  = S / NSTAT;                 // mean of y (bias-free)
        const float var = SS / NSTAT - my*my;        // var(y+b) == var(y)
        const float m   = my + (useb ? mb[tid] : 0.0f);
        const float rstd = rsqrtf(var + EPS_);
        const float sc = ldv<F32>(gamma, tid) * rstd;
        scale[tid] = sc;
        shift[tid] = ldv<F32>(beta, tid) - m * sc;
    }
}

template<bool F32>
__device__ __forceinline__ const u16* row_ptr(const u16* out1, const u16* halo,
                                              int b, int s, int t0)
{
    if (s >= t0 && s < t0 + TTILE)
        return &out1[((size_t)b*T_ + s) * Geo<F32>::STR];
    const int tile = s / TTILE, rem = s % TTILE;
    const int slot = rem < 4 ? rem : rem - 22;
    return &halo[(((size_t)b*10 + tile)*8 + slot) * ROWE];
}

// ---------------------------------------------------------------------------
// K3_temporal v2: producer/consumer pipeline, 512 threads (8 waves).
//   waves 0-3 ("compute"): z[t] = hsum[cur] @ Wt + bt (MFMA), BN2 stats,
//     stage z into zL[cur].
//   waves 4-7 ("window"): write z[t-1] (zL[cur^1]) to global; load row t+5,
//     h=relu(bn1(.)), update ring + per-thread hacc, build hsum[cur^1].
//   ONE barrier per t-step; global load latency hides under the MFMA phase.
//   LDS 48.6 KB -> 3 blocks/CU (24 waves).
// ---------------------------------------------------------------------------
template<bool F32>
__global__ __launch_bounds__(512, 4) void k3_temporal(
    const int* __restrict__ flag,
    u16* out1, const u16* __restrict__ halo,
    const u16* __restrict__ wtT, const void* bt,
    const float* __restrict__ sc1, const float* __restrict__ sh1,
    float* __restrict__ p2)
{
    if (flag[0] != (F32 ? 1 : 0)) return;
    const int STR = Geo<F32>::STR;

    __shared__ u16   ring[10*1600];     // h rows (bf16), 32 KB
    __shared__ f16   hsumH[2*2304];     // 2 x [32][72] f16, 9.2 KB
    __shared__ u16   zL[2][1600];       // z rows (f16), 6.4 KB
    __shared__ float redL[256];

    const int tid = threadIdx.x, lane = tid & 63, w = tid >> 6;   // w < 8
    const int b = blockIdx.y, t0 = blockIdx.x * TTILE;
    const bool isC = (w < 4);
    const int tidW = tid - 256;               // window-thread index
    const bool actW = (!isC) && (tidW < 200);

    // zero all of hsumH (pads stay 0; live rows overwritten below)
    for (int i = tid; i < 1152; i += 512) ((u32*)hsumH)[i] = 0u;

    // ---- window-wave state ----
    float hacc[8], S1[8], H1[8];
    int c0u = 0, vrow = 0;
    if (!isC) {
        const int tt = (tidW < 200) ? tidW : 0;
        c0u = (tt*8) & 63;
        vrow = tt >> 3;
        #pragma unroll
        for (int e = 0; e < 8; ++e) {
            hacc[e] = 0.0f; S1[e] = sc1[c0u+e]; H1[e] = sh1[c0u+e];
        }
    }

    // ---- compute-wave state ----
    const int ntp = w >> 1, mt = w & 1;       // meaningful for w<4
    f16x8 wfr[2][2];
    float btv[2] = {0.f, 0.f};
    if (isC) {
        #pragma unroll
        for (int ntl = 0; ntl < 2; ++ntl) {
            #pragma unroll
            for (int ks = 0; ks < 2; ++ks)
                wfr[ntl][ks] = *(const f16x8*)&wtT[
                    ((ntp*2+ntl)*16 + (lane & 15))*72 + ks*32 + ((lane >> 4) << 3)];
            btv[ntl] = ldv<F32>(bt, (ntp*2+ntl)*16 + (lane & 15));
        }
    }
    __syncthreads();   // hsumH zero done before prologue writes

    // ---- prologue: initial window [t0-4, t0+4] -> ring/hacc, hsum buf0 ----
    if (actW) {
        int slo = t0 - 4; if (slo < 0) slo = 0;
        for (int s = slo; s <= t0 + 4; ++s) {
            const u16* xr = row_ptr<F32>(out1, halo, b, s, t0);
            uint4 xv = *(const uint4*)&xr[tidW*8];
            const u16* xs = (const u16*)&xv;
            u16 hb[8];
            #pragma unroll
            for (int e = 0; e < 8; ++e) {
                float hv = fmaf(b2f(xs[e]), S1[e], H1[e]);
                hv = hv > 0.0f ? hv : 0.0f;
                hb[e] = f2b(hv);
                hacc[e] += b2f(hb[e]);
            }
            *(uint4*)&ring[(s%10)*1600 + tidW*8] = *(uint4*)hb;
        }
        u16 hs[8];
        #pragma unroll
        for (int e = 0; e < 8; ++e) hs[e] = h2u(hacc[e]);
        *(uint4*)&hsumH[vrow*72 + c0u] = *(uint4*)hs;
    }
    __syncthreads();

    float zs[2] = {0.f, 0.f}, zq[2] = {0.f, 0.f};

    for (int t = t0; t < t0 + TTILE; ++t) {
        const int cur = (t - t0) & 1;
        if (isC) {
            // ---- z[t] = hsum[cur] @ Wt + bt (MFMA), stats, stage zL[cur] ----
            const int arow = cur*2304 + (mt*16 + (lane & 15))*72 + ((lane >> 4) << 3);
            f16x8 a0 = *(const f16x8*)&hsumH[arow];
            f16x8 a1 = *(const f16x8*)&hsumH[arow + 32];
            #pragma unroll
            for (int ntl = 0; ntl < 2; ++ntl) {
                f32x4 d = f32x4{btv[ntl], btv[ntl], btv[ntl], btv[ntl]};
                d = __builtin_amdgcn_mfma_f32_16x16x32_f16(a0, wfr[ntl][0], d, 0, 0, 0);
                d = __builtin_amdgcn_mfma_f32_16x16x32_f16(a1, wfr[ntl][1], d, 0, 0, 0);
                const int cc = (ntp*2+ntl)*16 + (lane & 15);
                #pragma unroll
                for (int j = 0; j < 4; ++j) {
                    const int v = mt*16 + ((lane >> 4) << 2) + j;
                    if (v < 25) {
                        zs[ntl] += d[j]; zq[ntl] += d[j]*d[j];
                        zL[cur][v*64 + cc] = h2u(d[j]);
                    }
                }
            }
        } else {
            // ---- write z[t-1] to global (in place) ----
            if (t > t0 && actW)
                *(uint4*)&out1[((size_t)b*T_ + (t-1))*STR + tidW*8] =
                    *(const uint4*)&zL[cur^1][tidW*8];
            // ---- window update for t+1 -> hsum[cur^1] ----
            if (t + 1 < t0 + TTILE && actW) {
                const int snew = t + 5, sold = t - 4;
                if (snew < T_) {
                    const u16* xr = row_ptr<F32>(out1, halo, b, snew, t0);
                    uint4 xv = *(const uint4*)&xr[tidW*8];
                    const u16* xs = (const u16*)&xv;
                    u16 hb[8];
                    #pragma unroll
                    for (int e = 0; e < 8; ++e) {
                        float hv = fmaf(b2f(xs[e]), S1[e], H1[e]);
                        hv = hv > 0.0f ? hv : 0.0f;
                        hb[e] = f2b(hv);
                        hacc[e] += b2f(hb[e]);
                    }
                    *(uint4*)&ring[(snew%10)*1600 + tidW*8] = *(uint4*)hb;
                }
                if (sold >= 0) {
                    uint4 ov = *(const uint4*)&ring[(sold%10)*1600 + tidW*8];
                    const u16* os = (const u16*)&ov;
                    #pragma unroll
                    for (int e = 0; e < 8; ++e) hacc[e] -= b2f(os[e]);
                }
                u16 hs[8];
                #pragma unroll
                for (int e = 0; e < 8; ++e) hs[e] = h2u(hacc[e]);
                *(uint4*)&hsumH[(cur^1)*2304 + vrow*72 + c0u] = *(uint4*)hs;
            }
        }
        __syncthreads();
    }

    // ---- flush final z row (t0+TTILE-1 lives in zL[(TTILE-1)&1]) ----
    if (actW)
        *(uint4*)&out1[((size_t)b*T_ + (t0 + TTILE - 1))*STR + tidW*8] =
            *(const uint4*)&zL[(TTILE-1)&1][tidW*8];

    // ---- BN2 partials (compute waves only) ----
    #pragma unroll
    for (int ntl = 0; ntl < 2; ++ntl) {
        #pragma unroll
        for (int off = 16; off < 64; off <<= 1) {
            zs[ntl] += __shfl_xor(zs[ntl], off);
            zq[ntl] += __shfl_xor(zq[ntl], off);
        }
    }
    if (isC && lane < 16) {
        redL[w*32 + lane]            = zs[0];
        redL[w*32 + 16 + lane]       = zs[1];
        redL[128 + w*32 + lane]      = zq[0];
        redL[128 + w*32 + 16 + lane] = zq[1];
    }
    __syncthreads();
    if (tid < 64) {
        const int c = tid;
        const int ntg = c >> 4, pr = ntg >> 1, ntl = ntg & 1, l = c & 15;
        const int w0 = pr*2, w1 = pr*2 + 1;
        float s = redL[w0*32 + ntl*16 + l] + redL[w1*32 + ntl*16 + l];
        float q = redL[128 + w0*32 + ntl*16 + l] + redL[128 + w1*32 + ntl*16 + l];
        const int blk = blockIdx.y * (T_/TTILE) + blockIdx.x;
        p2[(size_t)blk*128 + c]      = s;
        p2[(size_t)blk*128 + 64 + c] = q;
    }
}

// ---------------------------------------------------------------------------
// K4_final: out = relu(z*sc2 + sh2) elementwise in place.
// ---------------------------------------------------------------------------
template<bool F32>
__global__ __launch_bounds__(256) void k4_final(
    const int* __restrict__ flag,
    const float* __restrict__ sc2, const float* __restrict__ sh2,
    void* outp)
{
    if (flag[0] != (F32 ? 1 : 0)) return;
    const int tid = threadIdx.x;

    if (!F32) {
        const size_t NQ = (size_t)ROWS * 200;         // uint4 count
        const size_t stride = (size_t)gridDim.x * blockDim.x;
        size_t q = (size_t)blockIdx.x * blockDim.x + tid;
        const int c0 = ((int)(q & 7)) * 8;            // invariant (stride%8==0)
        float S2[8], H2[8];
        #pragma unroll
        for (int e = 0; e < 8; ++e) { S2[e] = sc2[c0+e]; H2[e] = sh2[c0+e]; }
        u16* z = (u16*)outp;
        for (; q < NQ; q += stride) {
            union { uint4 u4; u16 s[8]; } zv;
            zv.u4 = *(const uint4*)&z[q*8];
            u16 ob[8];
            #pragma unroll
            for (int e = 0; e < 8; ++e) {
                float oo = fmaf(u2h(zv.s[e]), S2[e], H2[e]);
                ob[e] = f2b(oo > 0.0f ? oo : 0.0f);
            }
            *(uint4*)&z[q*8] = *(uint4*)ob;
        }
    } else {
        const int STR = Geo<true>::STR;
        const int c0u = (tid*8) & 63;
        float S2[8], H2[8];
        #pragma unroll
        for (int e = 0; e < 8; ++e) { S2[e] = sc2[c0u+e]; H2[e] = sh2[c0u+e]; }
        const int r0 = blockIdx.x * 10;
        u16* z = (u16*)outp;
        for (int r = 0; r < 10; ++r) {
            const int row = r0 + r;
            uint4 zv;
            if (tid < 200) zv = *(const uint4*)&z[(size_t)row*STR + tid*8];
            __syncthreads();
            if (tid < 200) {
                const u16* zp = (const u16*)&zv;
                float o[8];
                #pragma unroll
                for (int e = 0; e < 8; ++e) {
                    float oo = fmaf(u2h(zp[e]), S2[e], H2[e]);
                    o[e] = oo > 0.0f ? oo : 0.0f;
                }
                float* dst = (float*)outp + (size_t)row*ROWE + tid*8;
                *(float4*)dst     = float4{o[0], o[1], o[2], o[3]};
                *(float4*)(dst+4) = float4{o[4], o[5], o[6], o[7]};
            }
            __syncthreads();
        }
    }
}

// ---------------------------------------------------------------------------
extern "C" void kernel_launch(void* const* d_in, const int* in_sizes, int n_in,
                              void* d_out, int out_size, void* d_ws, size_t ws_size,
                              hipStream_t stream)
{
    const void* x     = d_in[0];
    const void* A     = d_in[1];
    const void* E     = d_in[2];
    const void* W1    = d_in[3];
    const void* b1    = d_in[4];
    const void* W2    = d_in[5];
    const void* b2    = d_in[6];
    const void* W3    = d_in[7];
    const void* b3    = d_in[8];
    const void* Wt    = d_in[9];
    const void* bt    = d_in[10];
    const void* gamma = d_in[11];
    const void* beta  = d_in[12];

    u16* out1 = (u16*)d_out;          // stage-1 staging lives in d_out

    // ws layout — front of d_ws; total ≈ 19.6 MB.
    int*   flag = (int*)d_ws;
    float* wsf  = (float*)d_ws;
    float* bsum = wsf + 4;
    float* sc1  = bsum + 64;
    float* sh1  = sc1 + 64;
    float* sc2  = sh1 + 64;
    float* sh2  = sc2 + 64;
    float* p1   = sh2 + 64;                       // K2BLK*128
    float* p2   = p1 + (size_t)K2BLK*128;         // 640*128
    float* q1   = p2 + 640*128;                   // 64*128
    float* q2   = q1 + 64*128;                    // 64*128
    u16*  halo  = (u16*)(q2 + 64*128);            // 5120*1600 u16 = 16.4 MB
    u16*  wcatT = halo + (size_t)5120*1600;       // 13824 f16
    u16*  anf   = wcatT + 13824;                  // 3072 f16
    u16*  wtT   = anf + 3072;                     // 4608 f16

    // host-side dtype dispatch from byte sizes; fallback: launch both variants
    const long NX = (long)B_*T_*V_*C_;            // 3,072,000 elements
    int mode = -1;
    if (n_in > 0) {
        if      (in_sizes[0] == (int)(NX*2)) mode = 0;   // bf16
        else if (in_sizes[0] == (int)(NX*4)) mode = 1;   // f32
    }
    const bool do_b = (mode != 1), do_f = (mode != 0);

    hipLaunchKernelGGL(k0_detect, dim3(1), dim3(256), 0, stream, W1, flag);

    if (do_b) hipLaunchKernelGGL(k1_prep<false>, dim3(1), dim3(256), 0, stream,
                       flag, A, E, W1, W2, W3, Wt, b1, b2, b3, anf, wcatT, wtT, bsum);
    if (do_f) hipLaunchKernelGGL(k1_prep<true>, dim3(1), dim3(256), 0, stream,
                       flag, A, E, W1, W2, W3, Wt, b1, b2, b3, anf, wcatT, wtT, bsum);

    if (do_b) hipLaunchKernelGGL(k2_mfma<false>, dim3(K2BLK), dim3(256), 0, stream,
                       flag, x, wcatT, anf, out1, halo, p1);
    if (do_f) hipLaunchKernelGGL(k2_mfma<true>, dim3(K2BLK), dim3(256), 0, stream,
                       flag, x, wcatT, anf, out1, halo, p1);

    hipLaunchKernelGGL(k_reduce, dim3(64), dim3(128), 0, stream, p1, K2BLK, q1);

    if (do_b) hipLaunchKernelGGL(k_bnstats<false>, dim3(1), dim3(256), 0, stream,
                       flag, q1, gamma, beta, bsum, 1, sc1, sh1);
    if (do_f) hipLaunchKernelGGL(k_bnstats<true>, dim3(1), dim3(256), 0, stream,
                       flag, q1, gamma, beta, bsum, 1, sc1, sh1);

    if (do_b) hipLaunchKernelGGL(k3_temporal<false>, dim3(10, 64), dim3(512), 0, stream,
                       flag, out1, halo, wtT, bt, sc1, sh1, p2);
    if (do_f) hipLaunchKernelGGL(k3_temporal<true>, dim3(10, 64), dim3(512), 0, stream,
                       flag, out1, halo, wtT, bt, sc1, sh1, p2);

    hipLaunchKernelGGL(k_reduce, dim3(64), dim3(128), 0, stream, p2, 640, q2);

    if (do_b) hipLaunchKernelGGL(k_bnstats<false>, dim3(1), dim3(256), 0, stream,
                       flag, q2, gamma, beta, bsum, 0, sc2, sh2);
    if (do_f) hipLaunchKernelGGL(k_bnstats<true>, dim3(1), dim3(256), 0, stream,
                       flag, q2, gamma, beta, bsum, 0, sc2, sh2);

    if (do_b) hipLaunchKernelGGL(k4_final<false>, dim3(2048), dim3(256), 0, stream,
                       flag, sc2, sh2, d_out);
    if (do_f) hipLaunchKernelGGL(k4_final<true>, dim3(1920), dim3(256), 0, stream,
                       flag, sc2, sh2, d_out);
}